// Round 2
// baseline (673.598 us; speedup 1.0000x reference)
//
#include <hip/hip_runtime.h>
#include <hip/hip_bf16.h>

// Problem constants
#define Bb 8
#define Ss 1024
#define Dd 1024
#define Hh 16
#define DHh 64
#define FFf 4096

typedef __hip_bfloat16 bf16;
typedef __attribute__((ext_vector_type(8))) __bf16 bf16x8;
typedef __attribute__((ext_vector_type(4))) float f32x4;

__device__ __forceinline__ unsigned short f2bu(float f) {
  __hip_bfloat16 h = __float2bfloat16(f);
  return __builtin_bit_cast(unsigned short, h);
}
__device__ __forceinline__ __bf16 f2b(float f) {
  __hip_bfloat16 h = __float2bfloat16(f);
  return __builtin_bit_cast(__bf16, h);
}

#define MFMA16(a, b, c) __builtin_amdgcn_mfma_f32_16x16x32_bf16((a), (b), (c), 0, 0, 0)

__device__ __forceinline__ void gl_lds16(const void* g, void* l) {
  __builtin_amdgcn_global_load_lds(
      (const __attribute__((address_space(1))) unsigned int*)g,
      (__attribute__((address_space(3))) unsigned int*)l, 16, 0, 0);
}

// ---------------------------------------------------------------------------
// f32 -> bf16 elementwise convert (vectorized: float4 in, 4xbf16 out)
// ---------------------------------------------------------------------------
__global__ __launch_bounds__(256) void f32_to_bf16_vec(const float* __restrict__ in,
                                                       bf16* __restrict__ out, int n4) {
  int i = blockIdx.x * 256 + threadIdx.x;
  if (i < n4) {
    float4 v = ((const float4*)in)[i];
    union { unsigned short u[4]; uint2 q; } r;
    r.u[0] = f2bu(v.x); r.u[1] = f2bu(v.y); r.u[2] = f2bu(v.z); r.u[3] = f2bu(v.w);
    ((uint2*)out)[i] = r.q;
  }
}

// ---------------------------------------------------------------------------
// Batched 32x32 LDS-tiled transpose: src f32 [R][C] -> dst bf16 [C][R]
// grid: (C/32, R/32, nbatch), block: 256
// ---------------------------------------------------------------------------
__global__ __launch_bounds__(256) void transpose_f32_bf16(const float* __restrict__ src,
                                                          bf16* __restrict__ dst,
                                                          int R, int C,
                                                          long sbatch, long dbatch) {
  __shared__ float tile[32][33];
  src += (size_t)blockIdx.z * sbatch;
  dst += (size_t)blockIdx.z * dbatch;
  int c0 = blockIdx.x * 32, r0 = blockIdx.y * 32;
  int tx = threadIdx.x & 31;
  int ty = threadIdx.x >> 5;  // 0..7
#pragma unroll
  for (int kk = 0; kk < 4; ++kk)
    tile[ty + kk * 8][tx] = src[(size_t)(r0 + ty + kk * 8) * C + c0 + tx];
  __syncthreads();
#pragma unroll
  for (int kk = 0; kk < 4; ++kk)
    dst[(size_t)(c0 + ty + kk * 8) * R + r0 + tx] = __float2bfloat16(tile[tx][ty + kk * 8]);
}

// ---------------------------------------------------------------------------
// GEMM: C[M,N] = A[M,K] * Bt[N,K]^T (+bias, epilogue variants)
// 128x128 tile, BK=32, 256 thr = 4 waves (2x2), each wave 64x64 = 4x4 frags
// of v_mfma_f32_16x16x32_bf16. LDS staged via global_load_lds w/ XOR seg
// swizzle (seg' = seg ^ (row&3)) to break the 64B-row-stride bank conflict.
// ---------------------------------------------------------------------------
enum { EPI_QKV = 0, EPI_WO = 1, EPI_FFN1 = 2, EPI_FFN2 = 3 };

template <int EPI>
__global__ __launch_bounds__(256) void gemm_bt(const bf16* __restrict__ A,
                                               const bf16* __restrict__ Bt,
                                               int M, int N, int K,
                                               const float* __restrict__ bias0,
                                               const float* __restrict__ bias1,
                                               const float* __restrict__ bias2,
                                               void* __restrict__ o0,
                                               void* __restrict__ o1,
                                               void* __restrict__ o2) {
  __shared__ __align__(16) unsigned char sm[16384];  // A: [0,8K), B: [8K,16K)
  const int t = threadIdx.x;
  const int lane = t & 63;
  const int w = t >> 6;       // wave 0..3
  const int wr = w >> 1;      // wave row 0..1
  const int wc = w & 1;       // wave col 0..1
  const int m0 = blockIdx.x * 128;
  const int n0 = blockIdx.y * 128;

  f32x4 acc[4][4];
  const f32x4 z4 = {0.f, 0.f, 0.f, 0.f};
#pragma unroll
  for (int i = 0; i < 4; ++i)
#pragma unroll
    for (int j = 0; j < 4; ++j) acc[i][j] = z4;

  const int srow = lane >> 2;  // 0..15 (staging row within wave's 16-row chunk)
  const int sseg = lane & 3;   // 0..3  (16B seg within 64B row)
  const int ks = lane >> 4;    // 0..3  (K seg for frag reads)
  const int rl = lane & 15;

  for (int kt = 0; kt < K; kt += 32) {
    __syncthreads();
#pragma unroll
    for (int r = 0; r < 2; ++r) {
      const int arow = r * 64 + w * 16 + srow;           // tile row 0..127
      const int aseg = sseg ^ (arow & 3);                // pre-swizzled source seg
      gl_lds16(A + ((size_t)(m0 + arow) * K + kt + aseg * 8),
               sm + r * 4096 + w * 1024);
      const int brow = r * 64 + w * 16 + srow;
      const int bseg = sseg ^ (brow & 3);
      gl_lds16(Bt + ((size_t)(n0 + brow) * K + kt + bseg * 8),
               sm + 8192 + r * 4096 + w * 1024);
    }
    __syncthreads();
    bf16x8 a[4], b[4];
#pragma unroll
    for (int i = 0; i < 4; ++i) {
      const int row = wr * 64 + i * 16 + rl;
      a[i] = *(const bf16x8*)(sm + row * 64 + (ks ^ (row & 3)) * 16);
      const int col = wc * 64 + i * 16 + rl;
      b[i] = *(const bf16x8*)(sm + 8192 + col * 64 + (ks ^ (col & 3)) * 16);
    }
#pragma unroll
    for (int i = 0; i < 4; ++i)
#pragma unroll
      for (int j = 0; j < 4; ++j) acc[i][j] = MFMA16(a[i], b[j], acc[i][j]);
  }

  // Epilogue. C/D frag layout: row = (lane>>4)*4 + p, col = lane&15.
  const int rbase = (lane >> 4) * 4;
  if constexpr (EPI == EPI_QKV) {
    const int which = n0 >> 10;  // 0=q,1=k,2=v (128-tile never straddles 1024)
    const float* bias = which == 0 ? bias0 : (which == 1 ? bias1 : bias2);
    bf16* dst = (bf16*)(which == 0 ? o0 : (which == 1 ? o1 : o2));
#pragma unroll
    for (int i = 0; i < 4; ++i) {
#pragma unroll
      for (int j = 0; j < 4; ++j) {
        const int gcol = n0 + wc * 64 + j * 16 + rl;
        const int cc = gcol & 1023;
        const int hh = cc >> 6, e = cc & 63;
        const float bval = bias[cc];
#pragma unroll
        for (int p = 0; p < 4; ++p) {
          const int grow = m0 + wr * 64 + i * 16 + rbase + p;
          const int bidx = grow >> 10, s = grow & 1023;
          dst[(((size_t)bidx * Hh + hh) * Ss + s) * DHh + e] =
              __float2bfloat16(acc[i][j][p] + bval);
        }
      }
    }
  } else if constexpr (EPI == EPI_WO || EPI == EPI_FFN2) {
    float* dst = (float*)o0;
#pragma unroll
    for (int i = 0; i < 4; ++i) {
#pragma unroll
      for (int j = 0; j < 4; ++j) {
        const int gcol = n0 + wc * 64 + j * 16 + rl;
        const float bval = bias0[gcol];
#pragma unroll
        for (int p = 0; p < 4; ++p) {
          const int grow = m0 + wr * 64 + i * 16 + rbase + p;
          dst[(size_t)grow * N + gcol] = acc[i][j][p] + bval;
        }
      }
    }
  } else {  // EPI_FFN1: ReLU -> bf16
    bf16* dst = (bf16*)o0;
#pragma unroll
    for (int i = 0; i < 4; ++i) {
#pragma unroll
      for (int j = 0; j < 4; ++j) {
        const int gcol = n0 + wc * 64 + j * 16 + rl;
        const float bval = bias0[gcol];
#pragma unroll
        for (int p = 0; p < 4; ++p) {
          const int grow = m0 + wr * 64 + i * 16 + rbase + p;
          dst[(size_t)grow * N + gcol] =
              __float2bfloat16(fmaxf(acc[i][j][p] + bval, 0.f));
        }
      }
    }
  }
}

// ---------------------------------------------------------------------------
// Flash attention: block = (b, h, 64 q-rows); 4 waves x 16 q-rows each.
// kv tiles of 32; K LDS padded [32][72], V^T LDS padded [64][40] (both keep
// 16B alignment for ds_read_b128, ~2-way banks). Online softmax; P goes via
// per-wave LDS scratch (C-frag layout -> A-frag layout).
// ---------------------------------------------------------------------------
__global__ __launch_bounds__(256) void attn_kernel(const bf16* __restrict__ q,
                                                   const bf16* __restrict__ k,
                                                   const bf16* __restrict__ v,
                                                   bf16* __restrict__ ctx) {
  __shared__ __align__(16) unsigned short Kl[32 * 72];
  __shared__ __align__(16) unsigned short Vt[64 * 40];
  __shared__ __align__(16) unsigned short Pl[4 * 16 * 40];

  const int b = blockIdx.z, h = blockIdx.y;
  const int q0 = blockIdx.x * 64;
  const size_t head = ((size_t)b * Hh + h) * Ss * DHh;
  const bf16* Qp = q + head;
  const bf16* Kp = k + head;
  const bf16* Vp = v + head;

  const int t = threadIdx.x;
  const int w = t >> 6;
  const int lane = t & 63;
  const int rl = lane & 15;
  const int ks = lane >> 4;  // 0..3

  // Q A-frags (row = lane&15, k = ks*8 + j), two K-chunks of 32
  const int qrow = q0 + w * 16 + rl;
  const bf16x8 aq0 = *(const bf16x8*)(Qp + (size_t)qrow * 64 + ks * 8);
  const bf16x8 aq1 = *(const bf16x8*)(Qp + (size_t)qrow * 64 + 32 + ks * 8);

  f32x4 o[4];
  const f32x4 z4 = {0.f, 0.f, 0.f, 0.f};
#pragma unroll
  for (int c = 0; c < 4; ++c) o[c] = z4;
  float m4[4] = {-1e30f, -1e30f, -1e30f, -1e30f};
  float l4[4] = {0.f, 0.f, 0.f, 0.f};

  const int strow = t >> 3;  // 0..31 staging row
  const int stseg = t & 7;   // 0..7 (8 bf16 each)
  unsigned short* Pw = Pl + w * 16 * 40;
  const float scale = 0.125f;  // 1/sqrt(64)

  for (int kv0 = 0; kv0 < Ss; kv0 += 32) {
    __syncthreads();
    // stage K tile [32][64] -> padded [32][72]
    bf16x8 kk = *(const bf16x8*)(Kp + (size_t)(kv0 + strow) * 64 + stseg * 8);
    *(bf16x8*)(Kl + strow * 72 + stseg * 8) = kk;
    // stage V tile transposed -> Vt[64][40]
    bf16x8 vv = *(const bf16x8*)(Vp + (size_t)(kv0 + strow) * 64 + stseg * 8);
#pragma unroll
    for (int j = 0; j < 8; ++j)
      Vt[(stseg * 8 + j) * 40 + strow] = __builtin_bit_cast(unsigned short, vv[j]);
    __syncthreads();

    // QK^T: scores [16 q x 32 kv] = 2 C-frags
    f32x4 s0 = z4, s1 = z4;
    {
      const bf16x8 bk00 = *(const bf16x8*)(Kl + rl * 72 + ks * 8);
      const bf16x8 bk01 = *(const bf16x8*)(Kl + rl * 72 + 32 + ks * 8);
      const bf16x8 bk10 = *(const bf16x8*)(Kl + (16 + rl) * 72 + ks * 8);
      const bf16x8 bk11 = *(const bf16x8*)(Kl + (16 + rl) * 72 + 32 + ks * 8);
      s0 = MFMA16(aq0, bk00, s0);
      s0 = MFMA16(aq1, bk01, s0);
      s1 = MFMA16(aq0, bk10, s1);
      s1 = MFMA16(aq1, bk11, s1);
    }

    float mx[4];
#pragma unroll
    for (int j = 0; j < 4; ++j) {
      s0[j] *= scale;
      s1[j] *= scale;
      mx[j] = fmaxf(s0[j], s1[j]);
    }
#pragma unroll
    for (int m = 1; m < 16; m <<= 1)
#pragma unroll
      for (int j = 0; j < 4; ++j) mx[j] = fmaxf(mx[j], __shfl_xor(mx[j], m, 64));

    float p0[4], p1[4], smr[4];
#pragma unroll
    for (int j = 0; j < 4; ++j) {
      const float mn = fmaxf(m4[j], mx[j]);
      const float corr = __expf(m4[j] - mn);
      m4[j] = mn;
      p0[j] = __expf(s0[j] - mn);
      p1[j] = __expf(s1[j] - mn);
      smr[j] = p0[j] + p1[j];
      l4[j] *= corr;
#pragma unroll
      for (int c = 0; c < 4; ++c) o[c][j] *= corr;
    }
#pragma unroll
    for (int m = 1; m < 16; m <<= 1)
#pragma unroll
      for (int j = 0; j < 4; ++j) smr[j] += __shfl_xor(smr[j], m, 64);
#pragma unroll
    for (int j = 0; j < 4; ++j) l4[j] += smr[j];

    // P (C-layout) -> per-wave LDS -> A-frag
#pragma unroll
    for (int j = 0; j < 4; ++j) {
      const int pr = ks * 4 + j;
      Pw[pr * 40 + rl] = f2bu(p0[j]);
      Pw[pr * 40 + 16 + rl] = f2bu(p1[j]);
    }
    asm volatile("s_waitcnt lgkmcnt(0)" ::: "memory");
    const bf16x8 pa = *(const bf16x8*)(Pw + rl * 40 + ks * 8);
#pragma unroll
    for (int c = 0; c < 4; ++c) {
      const bf16x8 vb = *(const bf16x8*)(Vt + (c * 16 + rl) * 40 + ks * 8);
      o[c] = MFMA16(pa, vb, o[c]);
    }
  }

  // write ctx [B,S,H,DH]
#pragma unroll
  for (int c = 0; c < 4; ++c) {
#pragma unroll
    for (int j = 0; j < 4; ++j) {
      const int sq = q0 + w * 16 + ks * 4 + j;
      const int dh = c * 16 + rl;
      ctx[(((size_t)b * Ss + sq) * Hh + h) * DHh + dh] =
          __float2bfloat16(o[c][j] / l4[j]);
    }
  }
}

// ---------------------------------------------------------------------------
// Fused residual + LayerNorm: out = LN(a + bsrc) * g + be
// one block per row (D=1024), 256 threads x float4
// ---------------------------------------------------------------------------
__global__ __launch_bounds__(256) void ln_fused(const float* __restrict__ a,
                                                const float* __restrict__ bsrc,
                                                const float* __restrict__ g,
                                                const float* __restrict__ be,
                                                float* __restrict__ of,
                                                bf16* __restrict__ ob) {
  const int row = blockIdx.x, t = threadIdx.x;
  const float4 va = ((const float4*)(a + (size_t)row * Dd))[t];
  const float4 vb = ((const float4*)(bsrc + (size_t)row * Dd))[t];
  const float x0 = va.x + vb.x, x1 = va.y + vb.y, x2 = va.z + vb.z, x3 = va.w + vb.w;
  float s = x0 + x1 + x2 + x3;
  float qq = x0 * x0 + x1 * x1 + x2 * x2 + x3 * x3;
#pragma unroll
  for (int m = 1; m < 64; m <<= 1) {
    s += __shfl_xor(s, m, 64);
    qq += __shfl_xor(qq, m, 64);
  }
  __shared__ float ss[4], sq2[4];
  if ((t & 63) == 0) {
    ss[t >> 6] = s;
    sq2[t >> 6] = qq;
  }
  __syncthreads();
  s = ss[0] + ss[1] + ss[2] + ss[3];
  qq = sq2[0] + sq2[1] + sq2[2] + sq2[3];
  const float mu = s * (1.0f / Dd);
  const float var = qq * (1.0f / Dd) - mu * mu;
  const float rs = rsqrtf(var + 1e-5f);
  const float4 gv = ((const float4*)g)[t];
  const float4 bv = ((const float4*)be)[t];
  const float y0 = (x0 - mu) * rs * gv.x + bv.x;
  const float y1 = (x1 - mu) * rs * gv.y + bv.y;
  const float y2 = (x2 - mu) * rs * gv.z + bv.z;
  const float y3 = (x3 - mu) * rs * gv.w + bv.w;
  if (of) ((float4*)(of + (size_t)row * Dd))[t] = make_float4(y0, y1, y2, y3);
  if (ob) {
    union { unsigned short u[4]; uint2 qv; } r;
    r.u[0] = f2bu(y0); r.u[1] = f2bu(y1); r.u[2] = f2bu(y2); r.u[3] = f2bu(y3);
    ((uint2*)(ob + (size_t)row * Dd))[t] = r.qv;
  }
}

// ---------------------------------------------------------------------------
extern "C" void kernel_launch(void* const* d_in, const int* in_sizes, int n_in,
                              void* d_out, int out_size, void* d_ws, size_t ws_size,
                              hipStream_t stream) {
  const float* x   = (const float*)d_in[0];
  const float* wq  = (const float*)d_in[1];
  const float* bq  = (const float*)d_in[2];
  const float* wk  = (const float*)d_in[3];
  const float* bk  = (const float*)d_in[4];
  const float* wv  = (const float*)d_in[5];
  const float* bv  = (const float*)d_in[6];
  const float* wo  = (const float*)d_in[7];
  const float* bo  = (const float*)d_in[8];
  const float* w1  = (const float*)d_in[9];
  const float* b1  = (const float*)d_in[10];
  const float* w2  = (const float*)d_in[11];
  const float* b2  = (const float*)d_in[12];
  const float* g1  = (const float*)d_in[13];
  const float* be1 = (const float*)d_in[14];
  const float* g2  = (const float*)d_in[15];
  const float* be2 = (const float*)d_in[16];
  float* out = (float*)d_out;

  char* ws = (char*)d_ws;
  const size_t MB = 1u << 20;
  bf16* qb    = (bf16*)(ws + 0);         // 16 MiB  [B,H,S,DH]
  bf16* kb    = (bf16*)(ws + 16 * MB);   // 16 MiB
  bf16* vvb   = (bf16*)(ws + 32 * MB);   // 16 MiB
  bf16* xb    = (bf16*)(ws + 48 * MB);   // 16 MiB  [B*S, D]
  bf16* hb    = (bf16*)(ws + 0);         // 64 MiB, reuses q/k/v/xb after attn
  bf16* ctx   = (bf16*)(ws + 64 * MB);   // 16 MiB  [B*S, H*DH]
  float* y    = (float*)(ws + 80 * MB);  // 32 MiB  f32 (attn-out, then ffn-out)
  float* x1f  = (float*)(ws + 112 * MB); // 32 MiB  f32 post-LN1
  bf16* x1b   = (bf16*)(ws + 144 * MB);  // 16 MiB  bf16 post-LN1
  bf16* btqkv = (bf16*)(ws + 160 * MB);  // 6 MiB   [3072][1024]
  bf16* wot   = (bf16*)(ws + 166 * MB);  // 2 MiB   [1024][1024]
  bf16* w1t   = (bf16*)(ws + 168 * MB);  // 8 MiB   [4096][1024]
  bf16* w2t   = (bf16*)(ws + 176 * MB);  // 8 MiB   [1024][4096]

  // --- weight/activation conversion ---
  f32_to_bf16_vec<<<8192, 256, 0, stream>>>(x, xb, Bb * Ss * Dd / 4);
  // per-head transpose [D,64] -> [64,D], 16 heads per matrix
  transpose_f32_bf16<<<dim3(2, 32, 16), 256, 0, stream>>>(wq, btqkv + 0 * 1048576,
                                                          Dd, DHh, 65536, 65536);
  transpose_f32_bf16<<<dim3(2, 32, 16), 256, 0, stream>>>(wk, btqkv + 1 * 1048576,
                                                          Dd, DHh, 65536, 65536);
  transpose_f32_bf16<<<dim3(2, 32, 16), 256, 0, stream>>>(wv, btqkv + 2 * 1048576,
                                                          Dd, DHh, 65536, 65536);
  transpose_f32_bf16<<<dim3(32, 32, 1), 256, 0, stream>>>(wo, wot, Hh * DHh, Dd, 0, 0);
  transpose_f32_bf16<<<dim3(128, 32, 1), 256, 0, stream>>>(w1, w1t, Dd, FFf, 0, 0);
  transpose_f32_bf16<<<dim3(32, 128, 1), 256, 0, stream>>>(w2, w2t, FFf, Dd, 0, 0);

  // --- QKV projection ---
  gemm_bt<EPI_QKV><<<dim3(64, 24), 256, 0, stream>>>(
      xb, btqkv, Bb * Ss, 3 * Hh * DHh, Dd, bq, bk, bv, qb, kb, vvb);

  // --- attention ---
  attn_kernel<<<dim3(Ss / 64, Hh, Bb), 256, 0, stream>>>(qb, kb, vvb, ctx);

  // --- output projection ---
  gemm_bt<EPI_WO><<<dim3(64, 8), 256, 0, stream>>>(
      ctx, wot, Bb * Ss, Dd, Hh * DHh, bo, nullptr, nullptr, y, nullptr, nullptr);

  // --- residual + LN1 ---
  ln_fused<<<Bb * Ss, 256, 0, stream>>>(x, y, g1, be1, x1f, x1b);

  // --- FFN ---
  gemm_bt<EPI_FFN1><<<dim3(64, 32), 256, 0, stream>>>(
      x1b, w1t, Bb * Ss, FFf, Dd, b1, nullptr, nullptr, hb, nullptr, nullptr);
  gemm_bt<EPI_FFN2><<<dim3(64, 8), 256, 0, stream>>>(
      hb, w2t, Bb * Ss, Dd, FFf, b2, nullptr, nullptr, y, nullptr, nullptr);

  // --- residual + LN2 -> out ---
  ln_fused<<<Bb * Ss, 256, 0, stream>>>(x1f, y, g2, be2, out, nullptr);
}

// Round 4
// 596.408 us; speedup vs baseline: 1.1294x; 1.1294x over previous
//
#include <hip/hip_runtime.h>
#include <hip/hip_bf16.h>

// Problem constants
#define Bb 8
#define Ss 1024
#define Dd 1024
#define Hh 16
#define DHh 64
#define FFf 4096

typedef __hip_bfloat16 bf16;
typedef __attribute__((ext_vector_type(8))) __bf16 bf16x8;
typedef __attribute__((ext_vector_type(4))) float f32x4;

__device__ __forceinline__ unsigned short f2bu(float f) {
  __hip_bfloat16 h = __float2bfloat16(f);
  return __builtin_bit_cast(unsigned short, h);
}

#define MFMA16(a, b, c) __builtin_amdgcn_mfma_f32_16x16x32_bf16((a), (b), (c), 0, 0, 0)

__device__ __forceinline__ void gl_lds16(const void* g, void* l) {
  __builtin_amdgcn_global_load_lds(
      (const __attribute__((address_space(1))) unsigned int*)g,
      (__attribute__((address_space(3))) unsigned int*)l, 16, 0, 0);
}

// ---------------------------------------------------------------------------
// f32 -> bf16 elementwise convert (vectorized: float4 in, 4xbf16 out)
// ---------------------------------------------------------------------------
__global__ __launch_bounds__(256) void f32_to_bf16_vec(const float* __restrict__ in,
                                                       bf16* __restrict__ out, int n4) {
  int i = blockIdx.x * 256 + threadIdx.x;
  if (i < n4) {
    float4 v = ((const float4*)in)[i];
    union { unsigned short u[4]; uint2 q; } r;
    r.u[0] = f2bu(v.x); r.u[1] = f2bu(v.y); r.u[2] = f2bu(v.z); r.u[3] = f2bu(v.w);
    ((uint2*)out)[i] = r.q;
  }
}

// ---------------------------------------------------------------------------
// Batched 32x32 LDS-tiled transpose: src f32 [R][C] -> dst bf16 [C][R]
// grid: (C/32, R/32, nbatch), block: 256
// ---------------------------------------------------------------------------
__global__ __launch_bounds__(256) void transpose_f32_bf16(const float* __restrict__ src,
                                                          bf16* __restrict__ dst,
                                                          int R, int C,
                                                          long sbatch, long dbatch) {
  __shared__ float tile[32][33];
  src += (size_t)blockIdx.z * sbatch;
  dst += (size_t)blockIdx.z * dbatch;
  int c0 = blockIdx.x * 32, r0 = blockIdx.y * 32;
  int tx = threadIdx.x & 31;
  int ty = threadIdx.x >> 5;  // 0..7
#pragma unroll
  for (int kk = 0; kk < 4; ++kk)
    tile[ty + kk * 8][tx] = src[(size_t)(r0 + ty + kk * 8) * C + c0 + tx];
  __syncthreads();
#pragma unroll
  for (int kk = 0; kk < 4; ++kk)
    dst[(size_t)(c0 + ty + kk * 8) * R + r0 + tx] = __float2bfloat16(tile[tx][ty + kk * 8]);
}

// ---------------------------------------------------------------------------
// GEMM: C[M,N] = A[M,K] * Bt[N,K]^T (+bias, epilogue variants)
// 128x128 tile, BK=32, 256 thr = 4 waves (2x2), each wave 64x64 = 4x4 frags
// of v_mfma_f32_16x16x32_bf16. LDS staged via global_load_lds w/ XOR seg
// swizzle (seg' = seg ^ (row&3)) to break the 64B-row-stride bank conflict.
// ---------------------------------------------------------------------------
enum { EPI_QKV = 0, EPI_WO = 1, EPI_FFN1 = 2, EPI_FFN2 = 3 };

template <int EPI>
__global__ __launch_bounds__(256) void gemm_bt(const bf16* __restrict__ A,
                                               const bf16* __restrict__ Bt,
                                               int M, int N, int K,
                                               const float* __restrict__ bias0,
                                               const float* __restrict__ bias1,
                                               const float* __restrict__ bias2,
                                               void* __restrict__ o0,
                                               void* __restrict__ o1,
                                               void* __restrict__ o2) {
  __shared__ __align__(16) unsigned char sm[16384];  // A: [0,8K), B: [8K,16K)
  const int t = threadIdx.x;
  const int lane = t & 63;
  const int w = t >> 6;       // wave 0..3
  const int wr = w >> 1;      // wave row 0..1
  const int wc = w & 1;       // wave col 0..1
  const int m0 = blockIdx.x * 128;
  const int n0 = blockIdx.y * 128;

  f32x4 acc[4][4];
  const f32x4 z4 = {0.f, 0.f, 0.f, 0.f};
#pragma unroll
  for (int i = 0; i < 4; ++i)
#pragma unroll
    for (int j = 0; j < 4; ++j) acc[i][j] = z4;

  const int srow = lane >> 2;  // 0..15 (staging row within wave's 16-row chunk)
  const int sseg = lane & 3;   // 0..3  (16B seg within 64B row)
  const int ks = lane >> 4;    // 0..3  (K seg for frag reads)
  const int rl = lane & 15;

  for (int kt = 0; kt < K; kt += 32) {
    __syncthreads();
#pragma unroll
    for (int r = 0; r < 2; ++r) {
      const int arow = r * 64 + w * 16 + srow;           // tile row 0..127
      const int aseg = sseg ^ (arow & 3);                // pre-swizzled source seg
      gl_lds16(A + ((size_t)(m0 + arow) * K + kt + aseg * 8),
               sm + r * 4096 + w * 1024);
      const int brow = r * 64 + w * 16 + srow;
      const int bseg = sseg ^ (brow & 3);
      gl_lds16(Bt + ((size_t)(n0 + brow) * K + kt + bseg * 8),
               sm + 8192 + r * 4096 + w * 1024);
    }
    __syncthreads();
    bf16x8 a[4], b[4];
#pragma unroll
    for (int i = 0; i < 4; ++i) {
      const int row = wr * 64 + i * 16 + rl;
      a[i] = *(const bf16x8*)(sm + row * 64 + (ks ^ (row & 3)) * 16);
      const int col = wc * 64 + i * 16 + rl;
      b[i] = *(const bf16x8*)(sm + 8192 + col * 64 + (ks ^ (col & 3)) * 16);
    }
#pragma unroll
    for (int i = 0; i < 4; ++i)
#pragma unroll
      for (int j = 0; j < 4; ++j) acc[i][j] = MFMA16(a[i], b[j], acc[i][j]);
  }

  // Epilogue. C/D frag layout: row = (lane>>4)*4 + p, col = lane&15.
  const int rbase = (lane >> 4) * 4;
  if constexpr (EPI == EPI_QKV) {
    const int which = n0 >> 10;  // 0=q,1=k,2=v (128-tile never straddles 1024)
    const float* bias = which == 0 ? bias0 : (which == 1 ? bias1 : bias2);
    bf16* dst = (bf16*)(which == 0 ? o0 : (which == 1 ? o1 : o2));
#pragma unroll
    for (int i = 0; i < 4; ++i) {
#pragma unroll
      for (int j = 0; j < 4; ++j) {
        const int gcol = n0 + wc * 64 + j * 16 + rl;
        const int cc = gcol & 1023;
        const int hh = cc >> 6, e = cc & 63;
        const float bval = bias[cc];
#pragma unroll
        for (int p = 0; p < 4; ++p) {
          const int grow = m0 + wr * 64 + i * 16 + rbase + p;
          const int bidx = grow >> 10, s = grow & 1023;
          if (which == 2) {
            // V stored transposed per head: [B,H,DH,S]
            dst[(((size_t)bidx * Hh + hh) * DHh + e) * Ss + s] =
                __float2bfloat16(acc[i][j][p] + bval);
          } else {
            dst[(((size_t)bidx * Hh + hh) * Ss + s) * DHh + e] =
                __float2bfloat16(acc[i][j][p] + bval);
          }
        }
      }
    }
  } else if constexpr (EPI == EPI_WO || EPI == EPI_FFN2) {
    float* dst = (float*)o0;
#pragma unroll
    for (int i = 0; i < 4; ++i) {
#pragma unroll
      for (int j = 0; j < 4; ++j) {
        const int gcol = n0 + wc * 64 + j * 16 + rl;
        const float bval = bias0[gcol];
#pragma unroll
        for (int p = 0; p < 4; ++p) {
          const int grow = m0 + wr * 64 + i * 16 + rbase + p;
          dst[(size_t)grow * N + gcol] = acc[i][j][p] + bval;
        }
      }
    }
  } else {  // EPI_FFN1: ReLU -> bf16
    bf16* dst = (bf16*)o0;
#pragma unroll
    for (int i = 0; i < 4; ++i) {
#pragma unroll
      for (int j = 0; j < 4; ++j) {
        const int gcol = n0 + wc * 64 + j * 16 + rl;
        const float bval = bias0[gcol];
#pragma unroll
        for (int p = 0; p < 4; ++p) {
          const int grow = m0 + wr * 64 + i * 16 + rbase + p;
          dst[(size_t)grow * N + gcol] =
              __float2bfloat16(fmaxf(acc[i][j][p] + bval, 0.f));
        }
      }
    }
  }
}

// ---------------------------------------------------------------------------
// Flash attention v2: block = (b, h, 64 q-rows); 4 waves x 16 q-rows each.
// KVBLK=64. K [S,DH] and V^T [DH,S] staged via global_load_lds into linear
// [64][64] LDS tiles with XOR seg-swizzle (seg ^= row&7; source pre-permuted,
// read swizzled -> minimal 8-phase ds_read_b128). P relayout via per-wave
// LDS [16][72]. Grid flattened 1D with XCD-locality decode: all 16 q-blocks
// of one (b,h) land on one XCD so K/V (256KB) stays L2-resident.
// ---------------------------------------------------------------------------
__global__ __launch_bounds__(256) void attn_kernel(const bf16* __restrict__ q,
                                                   const bf16* __restrict__ k,
                                                   const bf16* __restrict__ v,
                                                   bf16* __restrict__ ctx) {
  __shared__ __align__(16) unsigned short Kl[64 * 64];
  __shared__ __align__(16) unsigned short Vt[64 * 64];
  __shared__ __align__(16) unsigned short Pl[4 * 16 * 72];

  // XCD-locality decode: xcd = bid&7 (round-robin). 16 heads per XCD,
  // 16 consecutive slots = one head's 16 q-blocks.
  const int bid = blockIdx.x;
  const int xcd = bid & 7;
  const int s8 = bid >> 3;          // 0..255
  const int hg = xcd + 8 * (s8 >> 4);  // 0..127  (b*16+h)
  const int qi = s8 & 15;
  const int b = hg >> 4, h = hg & 15;
  const int q0 = qi * 64;
  const size_t head = (size_t)hg << 16;  // hg * S * DH
  const bf16* Qp = q + head;
  const bf16* Kp = k + head;
  const bf16* Vp = v + head;  // per-head [DH][S]

  const int t = threadIdx.x;
  const int w = t >> 6;
  const int lane = t & 63;
  const int rl = lane & 15;
  const int ks = lane >> 4;   // 0..3
  const int rx = rl & 7;

  // Q A-frags (row = lane&15, k = ks*8 + j), two 32-chunks of D=64
  const int qrow = q0 + w * 16 + rl;
  const bf16x8 aq0 = *(const bf16x8*)(Qp + (size_t)qrow * 64 + ks * 8);
  const bf16x8 aq1 = *(const bf16x8*)(Qp + (size_t)qrow * 64 + 32 + ks * 8);

  f32x4 o[4];
  const f32x4 z4 = {0.f, 0.f, 0.f, 0.f};
#pragma unroll
  for (int c = 0; c < 4; ++c) o[c] = z4;
  float m4[4] = {-1e30f, -1e30f, -1e30f, -1e30f};
  float l4[4] = {0.f, 0.f, 0.f, 0.f};

  const int srow8 = lane >> 3;  // 0..7
  const int sseg = lane & 7;    // 0..7 (16B segs in a 128B row)
  unsigned short* Pw = Pl + w * 16 * 72;
  const float scale = 0.125f;  // 1/sqrt(64)

  for (int kv0 = 0; kv0 < Ss; kv0 += 64) {
    __syncthreads();
    // stage K[kv0..+63][0..63] and V^T[0..63][kv0..+63]; each wave: rows
    // rb..rb+15 via two 1KB loads. Linear LDS dest; source seg pre-swizzled.
#pragma unroll
    for (int r = 0; r < 2; ++r) {
      const int rb = w * 16 + r * 8;
      const int row = rb + srow8;
      gl_lds16(Kp + (size_t)(kv0 + row) * 64 + (sseg ^ (row & 7)) * 8,
               Kl + rb * 64);
      gl_lds16(Vp + (size_t)row * Ss + kv0 + (sseg ^ (row & 7)) * 8,
               Vt + rb * 64);
    }
    __syncthreads();

    // QK^T: S[16q][64kv] = 4 C-frags
    f32x4 s4[4];
#pragma unroll
    for (int f = 0; f < 4; ++f) s4[f] = z4;
#pragma unroll
    for (int f = 0; f < 4; ++f) {
      const int row = f * 16 + rl;
      const bf16x8 b0 = *(const bf16x8*)(Kl + row * 64 + (ks ^ rx) * 8);
      const bf16x8 b1 = *(const bf16x8*)(Kl + row * 64 + ((4 + ks) ^ rx) * 8);
      s4[f] = MFMA16(aq0, b0, s4[f]);
      s4[f] = MFMA16(aq1, b1, s4[f]);
    }

    // online softmax (per q-row = (ks*4+j); kv spread over 16 rl lanes x 4 frags)
    float mx[4], sm[4];
#pragma unroll
    for (int j = 0; j < 4; ++j) {
      s4[0][j] *= scale; s4[1][j] *= scale; s4[2][j] *= scale; s4[3][j] *= scale;
      mx[j] = fmaxf(fmaxf(s4[0][j], s4[1][j]), fmaxf(s4[2][j], s4[3][j]));
    }
#pragma unroll
    for (int mm = 1; mm < 16; mm <<= 1)
#pragma unroll
      for (int j = 0; j < 4; ++j) mx[j] = fmaxf(mx[j], __shfl_xor(mx[j], mm, 64));
#pragma unroll
    for (int j = 0; j < 4; ++j) {
      const float mn = fmaxf(m4[j], mx[j]);
      const float corr = __expf(m4[j] - mn);
      m4[j] = mn;
#pragma unroll
      for (int f = 0; f < 4; ++f) s4[f][j] = __expf(s4[f][j] - mn);
      sm[j] = (s4[0][j] + s4[1][j]) + (s4[2][j] + s4[3][j]);
      l4[j] *= corr;
#pragma unroll
      for (int c = 0; c < 4; ++c) o[c][j] *= corr;
    }
#pragma unroll
    for (int mm = 1; mm < 16; mm <<= 1)
#pragma unroll
      for (int j = 0; j < 4; ++j) sm[j] += __shfl_xor(sm[j], mm, 64);
#pragma unroll
    for (int j = 0; j < 4; ++j) l4[j] += sm[j];

    // P (C-layout) -> per-wave LDS [16][72] -> A-frags
#pragma unroll
    for (int f = 0; f < 4; ++f)
#pragma unroll
      for (int j = 0; j < 4; ++j)
        Pw[(ks * 4 + j) * 72 + f * 16 + rl] = f2bu(s4[f][j]);
    asm volatile("s_waitcnt lgkmcnt(0)" ::: "memory");
    __builtin_amdgcn_sched_barrier(0);
    const bf16x8 pa0 = *(const bf16x8*)(Pw + rl * 72 + ks * 8);
    const bf16x8 pa1 = *(const bf16x8*)(Pw + rl * 72 + 32 + ks * 8);

    // PV: out[16q][64d] += P[16q][64kv] * V[64kv][64d]
#pragma unroll
    for (int c = 0; c < 4; ++c) {
      const int row = c * 16 + rl;
      const bf16x8 v0 = *(const bf16x8*)(Vt + row * 64 + (ks ^ rx) * 8);
      const bf16x8 v1 = *(const bf16x8*)(Vt + row * 64 + ((4 + ks) ^ rx) * 8);
      o[c] = MFMA16(pa0, v0, o[c]);
      o[c] = MFMA16(pa1, v1, o[c]);
    }
  }

  // write ctx [B,S,H,DH]
  float inv[4];
#pragma unroll
  for (int j = 0; j < 4; ++j) inv[j] = 1.0f / l4[j];
#pragma unroll
  for (int c = 0; c < 4; ++c) {
#pragma unroll
    for (int j = 0; j < 4; ++j) {
      const int sq = q0 + w * 16 + ks * 4 + j;
      const int dh = c * 16 + rl;
      ctx[(((size_t)b * Ss + sq) * Hh + h) * DHh + dh] =
          __float2bfloat16(o[c][j] * inv[j]);
    }
  }
}

// ---------------------------------------------------------------------------
// Fused residual + LayerNorm: out = LN(a + bsrc) * g + be
// one block per row (D=1024), 256 threads x float4
// ---------------------------------------------------------------------------
__global__ __launch_bounds__(256) void ln_fused(const float* __restrict__ a,
                                                const float* __restrict__ bsrc,
                                                const float* __restrict__ g,
                                                const float* __restrict__ be,
                                                float* __restrict__ of,
                                                bf16* __restrict__ ob) {
  const int row = blockIdx.x, t = threadIdx.x;
  const float4 va = ((const float4*)(a + (size_t)row * Dd))[t];
  const float4 vb = ((const float4*)(bsrc + (size_t)row * Dd))[t];
  const float x0 = va.x + vb.x, x1 = va.y + vb.y, x2 = va.z + vb.z, x3 = va.w + vb.w;
  float s = x0 + x1 + x2 + x3;
  float qq = x0 * x0 + x1 * x1 + x2 * x2 + x3 * x3;
#pragma unroll
  for (int m = 1; m < 64; m <<= 1) {
    s += __shfl_xor(s, m, 64);
    qq += __shfl_xor(qq, m, 64);
  }
  __shared__ float ss[4], sq2[4];
  if ((t & 63) == 0) {
    ss[t >> 6] = s;
    sq2[t >> 6] = qq;
  }
  __syncthreads();
  s = ss[0] + ss[1] + ss[2] + ss[3];
  qq = sq2[0] + sq2[1] + sq2[2] + sq2[3];
  const float mu = s * (1.0f / Dd);
  const float var = qq * (1.0f / Dd) - mu * mu;
  const float rs = rsqrtf(var + 1e-5f);
  const float4 gv = ((const float4*)g)[t];
  const float4 bv = ((const float4*)be)[t];
  const float y0 = (x0 - mu) * rs * gv.x + bv.x;
  const float y1 = (x1 - mu) * rs * gv.y + bv.y;
  const float y2 = (x2 - mu) * rs * gv.z + bv.z;
  const float y3 = (x3 - mu) * rs * gv.w + bv.w;
  if (of) ((float4*)(of + (size_t)row * Dd))[t] = make_float4(y0, y1, y2, y3);
  if (ob) {
    union { unsigned short u[4]; uint2 qv; } r;
    r.u[0] = f2bu(y0); r.u[1] = f2bu(y1); r.u[2] = f2bu(y2); r.u[3] = f2bu(y3);
    ((uint2*)(ob + (size_t)row * Dd))[t] = r.qv;
  }
}

// ---------------------------------------------------------------------------
extern "C" void kernel_launch(void* const* d_in, const int* in_sizes, int n_in,
                              void* d_out, int out_size, void* d_ws, size_t ws_size,
                              hipStream_t stream) {
  const float* x   = (const float*)d_in[0];
  const float* wq  = (const float*)d_in[1];
  const float* bq  = (const float*)d_in[2];
  const float* wk  = (const float*)d_in[3];
  const float* bk  = (const float*)d_in[4];
  const float* wv  = (const float*)d_in[5];
  const float* bv  = (const float*)d_in[6];
  const float* wo  = (const float*)d_in[7];
  const float* bo  = (const float*)d_in[8];
  const float* w1  = (const float*)d_in[9];
  const float* b1  = (const float*)d_in[10];
  const float* w2  = (const float*)d_in[11];
  const float* b2  = (const float*)d_in[12];
  const float* g1  = (const float*)d_in[13];
  const float* be1 = (const float*)d_in[14];
  const float* g2  = (const float*)d_in[15];
  const float* be2 = (const float*)d_in[16];
  float* out = (float*)d_out;

  char* ws = (char*)d_ws;
  const size_t MB = 1u << 20;
  bf16* qb    = (bf16*)(ws + 0);         // 16 MiB  [B,H,S,DH]
  bf16* kb    = (bf16*)(ws + 16 * MB);   // 16 MiB  [B,H,S,DH]
  bf16* vvb   = (bf16*)(ws + 32 * MB);   // 16 MiB  [B,H,DH,S]  (transposed!)
  bf16* xb    = (bf16*)(ws + 48 * MB);   // 16 MiB  [B*S, D]
  bf16* hb    = (bf16*)(ws + 0);         // 64 MiB, reuses q/k/v/xb after attn
  bf16* ctx   = (bf16*)(ws + 64 * MB);   // 16 MiB  [B*S, H*DH]
  float* y    = (float*)(ws + 80 * MB);  // 32 MiB  f32 (attn-out, then ffn-out)
  float* x1f  = (float*)(ws + 112 * MB); // 32 MiB  f32 post-LN1
  bf16* x1b   = (bf16*)(ws + 144 * MB);  // 16 MiB  bf16 post-LN1
  bf16* btqkv = (bf16*)(ws + 160 * MB);  // 6 MiB   [3072][1024]
  bf16* wot   = (bf16*)(ws + 166 * MB);  // 2 MiB   [1024][1024]
  bf16* w1t   = (bf16*)(ws + 168 * MB);  // 8 MiB   [4096][1024]
  bf16* w2t   = (bf16*)(ws + 176 * MB);  // 8 MiB   [1024][4096]

  // --- weight/activation conversion ---
  f32_to_bf16_vec<<<8192, 256, 0, stream>>>(x, xb, Bb * Ss * Dd / 4);
  // per-head transpose [D,64] -> [64,D], 16 heads per matrix
  transpose_f32_bf16<<<dim3(2, 32, 16), 256, 0, stream>>>(wq, btqkv + 0 * 1048576,
                                                          Dd, DHh, 65536, 65536);
  transpose_f32_bf16<<<dim3(2, 32, 16), 256, 0, stream>>>(wk, btqkv + 1 * 1048576,
                                                          Dd, DHh, 65536, 65536);
  transpose_f32_bf16<<<dim3(2, 32, 16), 256, 0, stream>>>(wv, btqkv + 2 * 1048576,
                                                          Dd, DHh, 65536, 65536);
  transpose_f32_bf16<<<dim3(32, 32, 1), 256, 0, stream>>>(wo, wot, Hh * DHh, Dd, 0, 0);
  transpose_f32_bf16<<<dim3(128, 32, 1), 256, 0, stream>>>(w1, w1t, Dd, FFf, 0, 0);
  transpose_f32_bf16<<<dim3(32, 128, 1), 256, 0, stream>>>(w2, w2t, FFf, Dd, 0, 0);

  // --- QKV projection (V written transposed per head) ---
  gemm_bt<EPI_QKV><<<dim3(64, 24), 256, 0, stream>>>(
      xb, btqkv, Bb * Ss, 3 * Hh * DHh, Dd, bq, bk, bv, qb, kb, vvb);

  // --- attention (1D grid, XCD-locality decode) ---
  attn_kernel<<<2048, 256, 0, stream>>>(qb, kb, vvb, ctx);

  // --- output projection ---
  gemm_bt<EPI_WO><<<dim3(64, 8), 256, 0, stream>>>(
      ctx, wot, Bb * Ss, Dd, Hh * DHh, bo, nullptr, nullptr, y, nullptr, nullptr);

  // --- residual + LN1 ---
  ln_fused<<<Bb * Ss, 256, 0, stream>>>(x, y, g1, be1, x1f, x1b);

  // --- FFN ---
  gemm_bt<EPI_FFN1><<<dim3(64, 32), 256, 0, stream>>>(
      x1b, w1t, Bb * Ss, FFf, Dd, b1, nullptr, nullptr, hb, nullptr, nullptr);
  gemm_bt<EPI_FFN2><<<dim3(64, 8), 256, 0, stream>>>(
      hb, w2t, Bb * Ss, Dd, FFf, b2, nullptr, nullptr, y, nullptr, nullptr);

  // --- residual + LN2 -> out ---
  ln_fused<<<Bb * Ss, 256, 0, stream>>>(x1f, y, g2, be2, out, nullptr);
}